// Round 1
// baseline (957.758 us; speedup 1.0000x reference)
//
#include <hip/hip_runtime.h>
#include <hip/hip_bf16.h>
#include <stdint.h>

typedef __bf16 bf16x8 __attribute__((ext_vector_type(8)));
typedef float f32x4 __attribute__((ext_vector_type(4)));
typedef unsigned short us8 __attribute__((ext_vector_type(8)));

__device__ __forceinline__ float bf2f(unsigned short u) {
    return __uint_as_float(((unsigned)u) << 16);
}
__device__ __forceinline__ unsigned short f2bf(float f) {
    __bf16 b = (__bf16)f;  // RNE
    return __builtin_bit_cast(unsigned short, b);
}

// ---------------------------------------------------------------------------
// Transpose + cast: in (K x N) f32  ->  out (N x K) bf16
// ---------------------------------------------------------------------------
__global__ __launch_bounds__(256) void transpose_cast(
    const float* __restrict__ in, unsigned short* __restrict__ out,
    int K, int N)
{
    __shared__ float tile[32][33];
    const int tx = threadIdx.x, ty = threadIdx.y;  // (32, 8)
    const int n0 = blockIdx.x * 32, k0 = blockIdx.y * 32;
    #pragma unroll
    for (int i = 0; i < 32; i += 8)
        tile[ty + i][tx] = in[(long)(k0 + ty + i) * N + n0 + tx];
    __syncthreads();
    #pragma unroll
    for (int i = 0; i < 32; i += 8)
        out[(long)(n0 + ty + i) * K + k0 + tx] = f2bf(tile[tx][ty + i]);
}

// ---------------------------------------------------------------------------
// GEMM: C(M,N) = A(M,K) @ BT(N,K)^T + bias(N)
// A: f32 (converted to bf16 during staging) or bf16.  BT/bias: bf16/f32.
// 128x128 tile, BK=64, 4 waves (2x2), 16x16x32 MFMA, XOR-swizzled LDS.
// ---------------------------------------------------------------------------
template<bool A_F32, bool OUT_BF16>
__global__ __launch_bounds__(256, 2)
void gemm_bt(const void* __restrict__ Ap, const unsigned short* __restrict__ BT,
             const float* __restrict__ bias, void* __restrict__ Cp,
             int M, int N, int K)
{
    __shared__ unsigned short sA[128 * 64];
    __shared__ unsigned short sB[128 * 64];
    const int tid = threadIdx.x;
    const int lane = tid & 63;
    const int wave = tid >> 6;
    const int wr = wave >> 1, wc = wave & 1;
    const long rowStart = (long)blockIdx.y * 128;
    const int colStart = blockIdx.x * 128;

    f32x4 acc[4][4] = {};

    for (int kt = 0; kt < K; kt += 64) {
        // stage A and B tiles (each 128 rows x 64 cols bf16 = 16KB)
        #pragma unroll
        for (int i = 0; i < 4; ++i) {
            const int o = (i * 256 + tid) * 16;   // linear dest byte in tile
            const int r = o >> 7;                 // tile row (128B rows)
            const int cb = o & 127;               // byte col within row
            const int od = o ^ ((r & 7) << 4);    // XOR swizzle (bank-conflict fix)
            us8 w;
            if constexpr (A_F32) {
                const float* ga = (const float*)Ap + (rowStart + r) * (long)K + kt + (cb >> 1);
                const f32x4 u0 = *(const f32x4*)ga;
                const f32x4 u1 = *(const f32x4*)(ga + 4);
                #pragma unroll
                for (int e = 0; e < 4; ++e) { w[e] = f2bf(u0[e]); w[e + 4] = f2bf(u1[e]); }
            } else {
                const unsigned short* ga = (const unsigned short*)Ap + (rowStart + r) * (long)K + kt + (cb >> 1);
                w = *(const us8*)ga;
            }
            *(us8*)((char*)sA + od) = w;
            const unsigned short* gb = BT + (colStart + r) * (long)K + kt + (cb >> 1);
            *(us8*)((char*)sB + od) = *(const us8*)gb;
        }
        __syncthreads();
        #pragma unroll
        for (int kk = 0; kk < 2; ++kk) {
            const int kb = kk * 64 + ((lane >> 4) << 4);  // byte k-offset in row
            bf16x8 af[4], bfr[4];
            #pragma unroll
            for (int mi = 0; mi < 4; ++mi) {
                const int row = wr * 64 + mi * 16 + (lane & 15);
                const int ad = (row * 128 + kb) ^ ((row & 7) << 4);
                af[mi] = *(const bf16x8*)((const char*)sA + ad);
            }
            #pragma unroll
            for (int ni = 0; ni < 4; ++ni) {
                const int row = wc * 64 + ni * 16 + (lane & 15);
                const int ad = (row * 128 + kb) ^ ((row & 7) << 4);
                bfr[ni] = *(const bf16x8*)((const char*)sB + ad);
            }
            #pragma unroll
            for (int mi = 0; mi < 4; ++mi)
                #pragma unroll
                for (int ni = 0; ni < 4; ++ni)
                    acc[mi][ni] = __builtin_amdgcn_mfma_f32_16x16x32_bf16(
                        af[mi], bfr[ni], acc[mi][ni], 0, 0, 0);
        }
        __syncthreads();
    }

    // epilogue: C/D frag layout col=lane&15, row=(lane>>4)*4+reg
    float bv[4];
    #pragma unroll
    for (int ni = 0; ni < 4; ++ni)
        bv[ni] = bias[colStart + wc * 64 + ni * 16 + (lane & 15)];
    #pragma unroll
    for (int mi = 0; mi < 4; ++mi) {
        #pragma unroll
        for (int ni = 0; ni < 4; ++ni) {
            const int col = colStart + wc * 64 + ni * 16 + (lane & 15);
            #pragma unroll
            for (int r = 0; r < 4; ++r) {
                const long row = rowStart + wr * 64 + mi * 16 + ((lane >> 4) << 2) + r;
                const float val = acc[mi][ni][r] + bv[ni];
                if constexpr (OUT_BF16)
                    ((unsigned short*)Cp)[row * N + col] = f2bf(val);
                else
                    ((float*)Cp)[row * N + col] = val;
            }
        }
    }
}

// ---------------------------------------------------------------------------
// Per-token head-mixing attention.
// qkv: (65536 tokens) x 3072 bf16  rows = [q(16x64) | k(16x64) | v(16x64)]
// For each token: s[h][g] = 0.125 * q[h]·k[g]; p = softmax_g(s);
// o[h][d] = sum_g p[h][g] v[g][d].
// Output written bf16 in the reference's scrambled layout:
//   row = n*4096 + h*256 + (t>>4), col = (t&15)*64 + d   (row stride 1024)
// One wave per token, 4 tokens per 256-thread block.
// ---------------------------------------------------------------------------
__global__ __launch_bounds__(256) void attn_kernel(
    const unsigned short* __restrict__ qkv, unsigned short* __restrict__ out)
{
    __shared__ unsigned short qkvs[4][3072];
    __shared__ float ps[4][256];
    __shared__ unsigned short os[4][1024];
    const int tid = threadIdx.x, lane = tid & 63, wave = tid >> 6;
    const long blockTok = (long)blockIdx.x * 4;

    // stage 4 contiguous token rows (24KB)
    const unsigned short* src = qkv + blockTok * 3072;
    unsigned short* dstBase = &qkvs[0][0];
    #pragma unroll
    for (int i = 0; i < 6; ++i) {
        const int o = (i * 256 + tid) * 8;
        *(us8*)&dstBase[o] = *(const us8*)&src[o];
    }
    __syncthreads();

    const unsigned short* q = &qkvs[wave][0];
    const unsigned short* kk = &qkvs[wave][1024];
    const unsigned short* vv = &qkvs[wave][2048];
    const int h = lane >> 2, g4 = lane & 3;

    // scores: each lane does 4 g's for its head
    float s[4] = {0.f, 0.f, 0.f, 0.f};
    #pragma unroll
    for (int d0 = 0; d0 < 64; d0 += 8) {
        const us8 q8 = *(const us8*)&q[h * 64 + d0];
        float qf[8];
        #pragma unroll
        for (int e = 0; e < 8; ++e) qf[e] = bf2f(q8[e]);
        #pragma unroll
        for (int j = 0; j < 4; ++j) {
            const us8 k8 = *(const us8*)&kk[(g4 * 4 + j) * 64 + d0];
            #pragma unroll
            for (int e = 0; e < 8; ++e) s[j] += qf[e] * bf2f(k8[e]);
        }
    }
    #pragma unroll
    for (int j = 0; j < 4; ++j) s[j] *= 0.125f;

    // softmax across the 4-lane group (16 g's per head)
    float mx = fmaxf(fmaxf(s[0], s[1]), fmaxf(s[2], s[3]));
    mx = fmaxf(mx, __shfl_xor(mx, 1, 64));
    mx = fmaxf(mx, __shfl_xor(mx, 2, 64));
    float p[4], sum = 0.f;
    #pragma unroll
    for (int j = 0; j < 4; ++j) { p[j] = expf(s[j] - mx); sum += p[j]; }
    sum += __shfl_xor(sum, 1, 64);
    sum += __shfl_xor(sum, 2, 64);
    const float inv = 1.f / sum;
    #pragma unroll
    for (int j = 0; j < 4; ++j) ps[wave][h * 16 + g4 * 4 + j] = p[j] * inv;
    __syncthreads();

    // PV: lane handles d in [db*16, db*16+16) for its head
    const int db = lane & 3;
    float o16[16] = {};
    #pragma unroll
    for (int gq = 0; gq < 4; ++gq) {
        const f32x4 pv = *(const f32x4*)&ps[wave][h * 16 + gq * 4];
        #pragma unroll
        for (int j = 0; j < 4; ++j) {
            const float pg = pv[j];
            const int g = gq * 4 + j;
            const us8 v8a = *(const us8*)&vv[g * 64 + db * 16];
            const us8 v8b = *(const us8*)&vv[g * 64 + db * 16 + 8];
            #pragma unroll
            for (int e = 0; e < 8; ++e) {
                o16[e]     += pg * bf2f(v8a[e]);
                o16[8 + e] += pg * bf2f(v8b[e]);
            }
        }
    }
    us8 w0, w1;
    #pragma unroll
    for (int e = 0; e < 8; ++e) { w0[e] = f2bf(o16[e]); w1[e] = f2bf(o16[8 + e]); }
    *(us8*)&os[wave][h * 64 + db * 16] = w0;
    *(us8*)&os[wave][h * 64 + db * 16 + 8] = w1;
    __syncthreads();

    // scatter 4 tokens x 2KB to scrambled layout, 16B chunks
    #pragma unroll
    for (int i = 0; i < 2; ++i) {
        const int c = i * 256 + tid;     // 0..511
        const int w2 = c >> 7;           // token slot in block
        const int cc = c & 127;          // 16B chunk within token (h=cc>>3, slot=cc&7)
        const long m = blockTok + w2;
        const long n_ = m >> 12;         // T = 4096
        const int t = (int)(m & 4095);
        const int hh = cc >> 3, slot = cc & 7;
        const long row = n_ * 4096 + hh * 256 + (t >> 4);
        const long colb = (long)(t & 15) * 128 + slot * 16;
        *(us8*)((char*)out + row * 2048 + colb) = *(const us8*)&os[w2][cc * 8];
    }
}

// ---------------------------------------------------------------------------
extern "C" void kernel_launch(void* const* d_in, const int* in_sizes, int n_in,
                              void* d_out, int out_size, void* d_ws, size_t ws_size,
                              hipStream_t stream) {
    const float* x      = (const float*)d_in[0];  // (16,4096,1024)
    const float* w_qkv  = (const float*)d_in[1];  // (1024,3072)
    const float* b_qkv  = (const float*)d_in[2];  // (3072)
    const float* w_proj = (const float*)d_in[3];  // (1024,1024)
    const float* b_proj = (const float*)d_in[4];  // (1024)

    const long M = 65536;  // 16*4096 tokens
    const size_t QKV_B   = (size_t)M * 3072 * 2;          // 402,653,184
    const size_t ATT_B   = (size_t)M * 1024 * 2;          // 134,217,728
    const size_t WQ_B    = 3072 * 1024 * 2;               //   6,291,456
    const size_t WP_B    = 1024 * 1024 * 2;               //   2,097,152
    if (ws_size < QKV_B + ATT_B + WQ_B + WP_B) return;    // need ~520MB

    char* ws = (char*)d_ws;
    unsigned short* qkv     = (unsigned short*)ws;
    unsigned short* attnout = (unsigned short*)(ws + QKV_B);
    unsigned short* wqkvT   = (unsigned short*)(ws + QKV_B + ATT_B);
    unsigned short* wprojT  = (unsigned short*)(ws + QKV_B + ATT_B + WQ_B);

    dim3 tb(32, 8);
    transpose_cast<<<dim3(3072 / 32, 1024 / 32), tb, 0, stream>>>(w_qkv, wqkvT, 1024, 3072);
    transpose_cast<<<dim3(1024 / 32, 1024 / 32), tb, 0, stream>>>(w_proj, wprojT, 1024, 1024);

    // qkv = x @ w_qkv + b_qkv   (bf16 out)
    gemm_bt<true, true><<<dim3(3072 / 128, M / 128), 256, 0, stream>>>(
        x, wqkvT, b_qkv, qkv, (int)M, 3072, 1024);

    // per-token attention -> scrambled attnout (bf16)
    attn_kernel<<<dim3(M / 4), 256, 0, stream>>>(qkv, attnout);

    // out = attnout @ w_proj + b_proj   (f32 out)
    gemm_bt<false, false><<<dim3(1024 / 128, M / 128), 256, 0, stream>>>(
        attnout, wprojT, b_proj, d_out, (int)M, 1024, 1024);
}

// Round 2
// 791.495 us; speedup vs baseline: 1.2101x; 1.2101x over previous
//
#include <hip/hip_runtime.h>
#include <hip/hip_bf16.h>
#include <stdint.h>

typedef __bf16 bf16x8 __attribute__((ext_vector_type(8)));
typedef float f32x4 __attribute__((ext_vector_type(4)));
typedef unsigned short us8 __attribute__((ext_vector_type(8)));

__device__ __forceinline__ float bf2f(unsigned short u) {
    return __uint_as_float(((unsigned)u) << 16);
}
__device__ __forceinline__ unsigned short f2bf(float f) {
    __bf16 b = (__bf16)f;  // RNE
    return __builtin_bit_cast(unsigned short, b);
}

__device__ __forceinline__ void gload16(const char* g, char* l) {
    __builtin_amdgcn_global_load_lds(
        (const __attribute__((address_space(1))) void*)g,
        (__attribute__((address_space(3))) void*)l, 16, 0, 0);
}

// ---------------------------------------------------------------------------
// Transpose + cast: in (K x N) f32  ->  out (N x K) bf16
// ---------------------------------------------------------------------------
__global__ __launch_bounds__(256) void transpose_cast(
    const float* __restrict__ in, unsigned short* __restrict__ out,
    int K, int N)
{
    __shared__ float tile[32][33];
    const int tx = threadIdx.x, ty = threadIdx.y;  // (32, 8)
    const int n0 = blockIdx.x * 32, k0 = blockIdx.y * 32;
    #pragma unroll
    for (int i = 0; i < 32; i += 8)
        tile[ty + i][tx] = in[(long)(k0 + ty + i) * N + n0 + tx];
    __syncthreads();
    #pragma unroll
    for (int i = 0; i < 32; i += 8)
        out[(long)(n0 + ty + i) * K + k0 + tx] = f2bf(tile[tx][ty + i]);
}

// ---------------------------------------------------------------------------
// Elementwise cast f32 -> bf16 (vectorized, grid-stride)
// ---------------------------------------------------------------------------
__global__ __launch_bounds__(256) void cast_f32_bf16(
    const float* __restrict__ in, unsigned short* __restrict__ out, long n)
{
    const long stride = (long)gridDim.x * 256 * 8;
    for (long i = ((long)blockIdx.x * 256 + threadIdx.x) * 8; i < n; i += stride) {
        const f32x4 u0 = *(const f32x4*)&in[i];
        const f32x4 u1 = *(const f32x4*)&in[i + 4];
        us8 w;
        #pragma unroll
        for (int e = 0; e < 4; ++e) { w[e] = f2bf(u0[e]); w[e + 4] = f2bf(u1[e]); }
        *(us8*)&out[i] = w;
    }
}

// ---------------------------------------------------------------------------
// GEMM: C(M,N) = A(M,K) @ BT(N,K)^T + bias(N)       (A, BT bf16; K == 1024)
// 256x256 tile, BK=64, 512 threads (8 waves, 2M x 4N), 128KB dbuf LDS,
// global_load_lds w/ pre-swizzled source, counted vmcnt(8), raw barriers,
// 4 phases/K-tile x 16 MFMA, setprio around MFMA clusters, XCD swizzle.
// ---------------------------------------------------------------------------
#define MFMA16x16(a, b, c) __builtin_amdgcn_mfma_f32_16x16x32_bf16(a, b, c, 0, 0, 0)

template<bool OUT_BF16>
__global__ __launch_bounds__(512, 2)
void gemm256(const unsigned short* __restrict__ A,   // M x K bf16
             const unsigned short* __restrict__ BT,  // N x K bf16
             const float* __restrict__ bias,
             void* __restrict__ Cp,
             int M, int N, int K)
{
    extern __shared__ char smem[];   // 131072: [buf0: A 32K | B 32K][buf1: ...]
    const int tid  = threadIdx.x;
    const int lane = tid & 63;
    const int w    = tid >> 6;      // wave 0..7
    const int wm   = w >> 2;        // 0..1 (M split)
    const int wn   = w & 3;         // 0..3 (N split)

    // XCD-bijective swizzle (launcher guarantees gridDim.x % 8 == 0)
    const int nwg  = gridDim.x;
    const int bid0 = blockIdx.x;
    const int bid  = (bid0 & 7) * (nwg >> 3) + (bid0 >> 3);
    const int nbx  = N >> 8;
    const int bx   = bid % nbx, by = bid / nbx;
    const long rowStart = (long)by * 256;
    const int  colStart = bx * 256;

    const int  KT = K >> 6;          // 16
    const long Kb = (long)K * 2;     // row stride bytes

    // ---- staging: instr (mat, j) covers tile rows j*64 + w*8 + (lane>>3) ----
    const int srow = w * 8 + (lane >> 3);
    const int scol = ((lane & 7) ^ (lane >> 3)) << 4;   // inverse-swizzled src col
    const char* aStage = (const char*)A  + (rowStart + srow) * Kb + scol;
    const char* bStage = (const char*)BT + ((long)colStart + srow) * Kb + scol;
    const int ldsW = w * 1024;

    // ---- fragment-read offsets (swizzled) ----
    const int fr = lane & 15;
    const int kq = lane >> 4;                      // 0..3
    const int kswz0 = (kq * 16)      ^ ((fr & 7) << 4);
    const int kswz1 = (64 + kq * 16) ^ ((fr & 7) << 4);
    const int aRowBase = (wm * 128 + fr) * 128;            // bytes, A region
    const int bRowBase = (wn * 64 + fr) * 128 + 32768;     // bytes, B region

    f32x4 acc[8][4] = {};

    // prologue: stage K-tiles 0 (buf0) and 1 (buf1): 8 loads/thread each
    #pragma unroll
    for (int tt = 0; tt < 2; ++tt) {
        #pragma unroll
        for (int j = 0; j < 4; ++j)
            gload16(aStage + (long)j * 64 * Kb + (long)tt * 128,
                    smem + tt * 65536 + j * 8192 + ldsW);
        #pragma unroll
        for (int j = 0; j < 4; ++j)
            gload16(bStage + (long)j * 64 * Kb + (long)tt * 128,
                    smem + tt * 65536 + 32768 + j * 8192 + ldsW);
    }

    #pragma unroll 2
    for (int t = 0; t < KT; ++t) {
        const int bufOff = (t & 1) * 65536;
        // tile-t loads complete (8 newest — tile t+1's — stay in flight)
        if (t < KT - 1) asm volatile("s_waitcnt vmcnt(8)");
        else            asm volatile("s_waitcnt vmcnt(0)");
        __builtin_amdgcn_s_barrier();
        __builtin_amdgcn_sched_barrier(0);

        // ---- P0: A[0..3] x B[0..1] ----
        bf16x8 a0[4][2], b01[2][2];
        #pragma unroll
        for (int mi = 0; mi < 4; ++mi) {
            a0[mi][0] = *(const bf16x8*)(smem + bufOff + aRowBase + mi * 2048 + kswz0);
            a0[mi][1] = *(const bf16x8*)(smem + bufOff + aRowBase + mi * 2048 + kswz1);
        }
        #pragma unroll
        for (int ni = 0; ni < 2; ++ni) {
            b01[ni][0] = *(const bf16x8*)(smem + bufOff + bRowBase + ni * 2048 + kswz0);
            b01[ni][1] = *(const bf16x8*)(smem + bufOff + bRowBase + ni * 2048 + kswz1);
        }
        __builtin_amdgcn_s_setprio(1);
        #pragma unroll
        for (int mi = 0; mi < 4; ++mi)
            #pragma unroll
            for (int ni = 0; ni < 2; ++ni) {
                acc[mi][ni] = MFMA16x16(a0[mi][0], b01[ni][0], acc[mi][ni]);
                acc[mi][ni] = MFMA16x16(a0[mi][1], b01[ni][1], acc[mi][ni]);
            }
        __builtin_amdgcn_s_setprio(0);
        __builtin_amdgcn_s_barrier();
        __builtin_amdgcn_sched_barrier(0);

        // ---- P1: A[0..3] x B[2..3] ----
        bf16x8 b23[2][2];
        #pragma unroll
        for (int nj = 0; nj < 2; ++nj) {
            b23[nj][0] = *(const bf16x8*)(smem + bufOff + bRowBase + (2 + nj) * 2048 + kswz0);
            b23[nj][1] = *(const bf16x8*)(smem + bufOff + bRowBase + (2 + nj) * 2048 + kswz1);
        }
        __builtin_amdgcn_s_setprio(1);
        #pragma unroll
        for (int mi = 0; mi < 4; ++mi)
            #pragma unroll
            for (int nj = 0; nj < 2; ++nj) {
                acc[mi][2 + nj] = MFMA16x16(a0[mi][0], b23[nj][0], acc[mi][2 + nj]);
                acc[mi][2 + nj] = MFMA16x16(a0[mi][1], b23[nj][1], acc[mi][2 + nj]);
            }
        __builtin_amdgcn_s_setprio(0);
        __builtin_amdgcn_s_barrier();
        __builtin_amdgcn_sched_barrier(0);
        // A rows [0,64) & [128,192) of this buf are dead -> stage tile t+2
        if (t + 2 < KT) {
            gload16(aStage + (long)0 * 64 * Kb + (long)(t + 2) * 128,
                    smem + bufOff + 0 * 8192 + ldsW);
            gload16(aStage + (long)2 * 64 * Kb + (long)(t + 2) * 128,
                    smem + bufOff + 2 * 8192 + ldsW);
        }

        // ---- P2: A[4..7] x B[2..3] ----
        bf16x8 a4[4][2];
        #pragma unroll
        for (int mi = 0; mi < 4; ++mi) {
            a4[mi][0] = *(const bf16x8*)(smem + bufOff + aRowBase + (4 + mi) * 2048 + kswz0);
            a4[mi][1] = *(const bf16x8*)(smem + bufOff + aRowBase + (4 + mi) * 2048 + kswz1);
        }
        __builtin_amdgcn_s_setprio(1);
        #pragma unroll
        for (int mi = 0; mi < 4; ++mi)
            #pragma unroll
            for (int nj = 0; nj < 2; ++nj) {
                acc[4 + mi][2 + nj] = MFMA16x16(a4[mi][0], b23[nj][0], acc[4 + mi][2 + nj]);
                acc[4 + mi][2 + nj] = MFMA16x16(a4[mi][1], b23[nj][1], acc[4 + mi][2 + nj]);
            }
        __builtin_amdgcn_s_setprio(0);
        __builtin_amdgcn_s_barrier();
        __builtin_amdgcn_sched_barrier(0);
        // all B reads and remaining A reads of this buf are done -> stage rest
        if (t + 2 < KT) {
            #pragma unroll
            for (int j = 0; j < 4; ++j)
                gload16(bStage + (long)j * 64 * Kb + (long)(t + 2) * 128,
                        smem + bufOff + 32768 + j * 8192 + ldsW);
            gload16(aStage + (long)1 * 64 * Kb + (long)(t + 2) * 128,
                    smem + bufOff + 1 * 8192 + ldsW);
            gload16(aStage + (long)3 * 64 * Kb + (long)(t + 2) * 128,
                    smem + bufOff + 3 * 8192 + ldsW);
        }

        // ---- P3: A[4..7] x B[0..1] (registers only) ----
        __builtin_amdgcn_s_setprio(1);
        #pragma unroll
        for (int mi = 0; mi < 4; ++mi)
            #pragma unroll
            for (int ni = 0; ni < 2; ++ni) {
                acc[4 + mi][ni] = MFMA16x16(a4[mi][0], b01[ni][0], acc[4 + mi][ni]);
                acc[4 + mi][ni] = MFMA16x16(a4[mi][1], b01[ni][1], acc[4 + mi][ni]);
            }
        __builtin_amdgcn_s_setprio(0);
        __builtin_amdgcn_sched_barrier(0);
        // no barrier here: next iteration opens with vmcnt + barrier
    }

    // ---- epilogue: C/D frag layout col=lane&15, row=(lane>>4)*4+e ----
    float bv[4];
    #pragma unroll
    for (int ni = 0; ni < 4; ++ni)
        bv[ni] = bias[colStart + wn * 64 + ni * 16 + fr];
    #pragma unroll
    for (int mi = 0; mi < 8; ++mi) {
        #pragma unroll
        for (int ni = 0; ni < 4; ++ni) {
            const int col = colStart + wn * 64 + ni * 16 + fr;
            #pragma unroll
            for (int e = 0; e < 4; ++e) {
                const long row = rowStart + wm * 128 + mi * 16 + kq * 4 + e;
                const float val = acc[mi][ni][e] + bv[ni];
                if constexpr (OUT_BF16)
                    ((unsigned short*)Cp)[row * N + col] = f2bf(val);
                else
                    ((float*)Cp)[row * N + col] = val;
            }
        }
    }
}

// ---------------------------------------------------------------------------
// Per-token head-mixing attention (unchanged from verified round-0 kernel).
// ---------------------------------------------------------------------------
__global__ __launch_bounds__(256) void attn_kernel(
    const unsigned short* __restrict__ qkv, unsigned short* __restrict__ out)
{
    __shared__ unsigned short qkvs[4][3072];
    __shared__ float ps[4][256];
    __shared__ unsigned short os[4][1024];
    const int tid = threadIdx.x, lane = tid & 63, wave = tid >> 6;
    const long blockTok = (long)blockIdx.x * 4;

    const unsigned short* src = qkv + blockTok * 3072;
    unsigned short* dstBase = &qkvs[0][0];
    #pragma unroll
    for (int i = 0; i < 6; ++i) {
        const int o = (i * 256 + tid) * 8;
        *(us8*)&dstBase[o] = *(const us8*)&src[o];
    }
    __syncthreads();

    const unsigned short* q = &qkvs[wave][0];
    const unsigned short* kk = &qkvs[wave][1024];
    const unsigned short* vv = &qkvs[wave][2048];
    const int h = lane >> 2, g4 = lane & 3;

    float s[4] = {0.f, 0.f, 0.f, 0.f};
    #pragma unroll
    for (int d0 = 0; d0 < 64; d0 += 8) {
        const us8 q8 = *(const us8*)&q[h * 64 + d0];
        float qf[8];
        #pragma unroll
        for (int e = 0; e < 8; ++e) qf[e] = bf2f(q8[e]);
        #pragma unroll
        for (int j = 0; j < 4; ++j) {
            const us8 k8 = *(const us8*)&kk[(g4 * 4 + j) * 64 + d0];
            #pragma unroll
            for (int e = 0; e < 8; ++e) s[j] += qf[e] * bf2f(k8[e]);
        }
    }
    #pragma unroll
    for (int j = 0; j < 4; ++j) s[j] *= 0.125f;

    float mx = fmaxf(fmaxf(s[0], s[1]), fmaxf(s[2], s[3]));
    mx = fmaxf(mx, __shfl_xor(mx, 1, 64));
    mx = fmaxf(mx, __shfl_xor(mx, 2, 64));
    float p[4], sum = 0.f;
    #pragma unroll
    for (int j = 0; j < 4; ++j) { p[j] = expf(s[j] - mx); sum += p[j]; }
    sum += __shfl_xor(sum, 1, 64);
    sum += __shfl_xor(sum, 2, 64);
    const float inv = 1.f / sum;
    #pragma unroll
    for (int j = 0; j < 4; ++j) ps[wave][h * 16 + g4 * 4 + j] = p[j] * inv;
    __syncthreads();

    const int db = lane & 3;
    float o16[16] = {};
    #pragma unroll
    for (int gq = 0; gq < 4; ++gq) {
        const f32x4 pv = *(const f32x4*)&ps[wave][h * 16 + gq * 4];
        #pragma unroll
        for (int j = 0; j < 4; ++j) {
            const float pg = pv[j];
            const int g = gq * 4 + j;
            const us8 v8a = *(const us8*)&vv[g * 64 + db * 16];
            const us8 v8b = *(const us8*)&vv[g * 64 + db * 16 + 8];
            #pragma unroll
            for (int e = 0; e < 8; ++e) {
                o16[e]     += pg * bf2f(v8a[e]);
                o16[8 + e] += pg * bf2f(v8b[e]);
            }
        }
    }
    us8 w0, w1;
    #pragma unroll
    for (int e = 0; e < 8; ++e) { w0[e] = f2bf(o16[e]); w1[e] = f2bf(o16[8 + e]); }
    *(us8*)&os[wave][h * 64 + db * 16] = w0;
    *(us8*)&os[wave][h * 64 + db * 16 + 8] = w1;
    __syncthreads();

    #pragma unroll
    for (int i = 0; i < 2; ++i) {
        const int c = i * 256 + tid;
        const int w2 = c >> 7;
        const int cc = c & 127;
        const long m = blockTok + w2;
        const long n_ = m >> 12;
        const int t = (int)(m & 4095);
        const int hh = cc >> 3, slot = cc & 7;
        const long row = n_ * 4096 + hh * 256 + (t >> 4);
        const long colb = (long)(t & 15) * 128 + slot * 16;
        *(us8*)((char*)out + row * 2048 + colb) = *(const us8*)&os[w2][cc * 8];
    }
}

// ---------------------------------------------------------------------------
extern "C" void kernel_launch(void* const* d_in, const int* in_sizes, int n_in,
                              void* d_out, int out_size, void* d_ws, size_t ws_size,
                              hipStream_t stream) {
    const float* x      = (const float*)d_in[0];  // (16,4096,1024)
    const float* w_qkv  = (const float*)d_in[1];  // (1024,3072)
    const float* b_qkv  = (const float*)d_in[2];  // (3072)
    const float* w_proj = (const float*)d_in[3];  // (1024,1024)
    const float* b_proj = (const float*)d_in[4];  // (1024)

    const long M = 65536;  // 16*4096 tokens
    const size_t QKV_B = (size_t)M * 3072 * 2;    // 402,653,184
    const size_t XB_B  = (size_t)M * 1024 * 2;    // 134,217,728 (x-bf16, then attnout)
    const size_t WQ_B  = 3072 * 1024 * 2;
    const size_t WP_B  = 1024 * 1024 * 2;
    if (ws_size < QKV_B + XB_B + WQ_B + WP_B) return;  // ~545MB

    char* ws = (char*)d_ws;
    unsigned short* qkv    = (unsigned short*)ws;
    unsigned short* xb     = (unsigned short*)(ws + QKV_B);          // also attnout
    unsigned short* wqkvT  = (unsigned short*)(ws + QKV_B + XB_B);
    unsigned short* wprojT = (unsigned short*)(ws + QKV_B + XB_B + WQ_B);

    hipFuncSetAttribute((const void*)gemm256<true>,
                        hipFuncAttributeMaxDynamicSharedMemorySize, 131072);
    hipFuncSetAttribute((const void*)gemm256<false>,
                        hipFuncAttributeMaxDynamicSharedMemorySize, 131072);

    dim3 tb(32, 8);
    transpose_cast<<<dim3(3072 / 32, 1024 / 32), tb, 0, stream>>>(w_qkv, wqkvT, 1024, 3072);
    transpose_cast<<<dim3(1024 / 32, 1024 / 32), tb, 0, stream>>>(w_proj, wprojT, 1024, 1024);
    cast_f32_bf16<<<2048, 256, 0, stream>>>(x, xb, M * 1024);

    // qkv = x @ w_qkv + b_qkv   (bf16 out); grid 12*256=3072 (%8==0)
    gemm256<true><<<dim3((3072 / 256) * (M / 256)), 512, 131072, stream>>>(
        xb, wqkvT, b_qkv, qkv, (int)M, 3072, 1024);

    // per-token attention -> scrambled attnout (bf16), reusing xb
    attn_kernel<<<dim3(M / 4), 256, 0, stream>>>(qkv, xb);

    // out = attnout @ w_proj + b_proj   (f32 out); grid 4*256=1024 (%8==0)
    gemm256<false><<<dim3((1024 / 256) * (M / 256)), 512, 131072, stream>>>(
        xb, wprojT, b_proj, d_out, (int)M, 1024, 1024);
}